// Round 13
// baseline (105.635 us; speedup 1.0000x reference)
//
#include <hip/hip_runtime.h>
#include <math.h>

#define N_SAMPLES 16384
#define FEAT 2048
#define NCLS 1000
#define CPAD 1024
#define COLB 2048
#define ROWS_PER_B (N_SAMPLES / COLB)  // 8
#define MAXCLS 64  // max rows/class; Poisson(16.4) tail at 64 ~ 1e-18

// ---------------- workspace layout ----------------
// part_ov : float[COLB*FEAT]   colsum partials (16 MB)
// overall : float[FEAT]
// pst/psw : float[CPAD]
// counts/offsets : int[CPAD]; perm : int[N_SAMPLES]
// (no memset needed: everything plain-stored before read)

// K1: block 0 sorts labels; blocks 1..COLB colsum 8 contiguous rows each into
// part_ov. NO bf16 shadow store (R13 ablation: k1's 83-MB store stream was the
// suspected 1.9-TB/s cap; pass 2 reads f32 feat from L3 instead).
__global__ __launch_bounds__(256) void k1_col_sort(
    const float* __restrict__ feat, const int* __restrict__ labels,
    float* __restrict__ part_ov, int* __restrict__ counts,
    int* __restrict__ offsets, int* __restrict__ perm) {
  const int t = threadIdx.x, lane = t & 63, w = t >> 6;
  if (blockIdx.x == 0) {
    // sort: hist -> scan -> scatter (proven R5 block)
    __shared__ int h[CPAD];
    __shared__ int cur[CPAD];
    __shared__ int wtot[4];
    for (int i = t; i < CPAD; i += 256) h[i] = 0;
    __syncthreads();
    const int4* lb = (const int4*)labels;
    for (int j = t; j < N_SAMPLES / 4; j += 256) {
      int4 q = lb[j];
      atomicAdd(&h[q.x], 1);
      atomicAdd(&h[q.y], 1);
      atomicAdd(&h[q.z], 1);
      atomicAdd(&h[q.w], 1);
    }
    __syncthreads();
    const int b4 = 4 * t;  // thread t owns classes [4t,4t+4)
    const int e0 = h[b4], e1 = h[b4 + 1], e2 = h[b4 + 2], e3 = h[b4 + 3];
    const int ssum = e0 + e1 + e2 + e3;
    int v = ssum;
    for (int off = 1; off < 64; off <<= 1) {
      int p = __shfl_up(v, off);
      if (lane >= off) v += p;
    }
    if (lane == 63) wtot[w] = v;
    __syncthreads();
    int wb = 0;
    for (int i = 0; i < w; ++i) wb += wtot[i];
    const int excl = wb + v - ssum;
    counts[b4] = e0; counts[b4 + 1] = e1; counts[b4 + 2] = e2; counts[b4 + 3] = e3;
    offsets[b4] = excl;
    offsets[b4 + 1] = excl + e0;
    offsets[b4 + 2] = excl + e0 + e1;
    offsets[b4 + 3] = excl + e0 + e1 + e2;
    cur[b4] = excl;
    cur[b4 + 1] = excl + e0;
    cur[b4 + 2] = excl + e0 + e1;
    cur[b4 + 3] = excl + e0 + e1 + e2;
    __syncthreads();
    for (int j = t; j < N_SAMPLES / 4; j += 256) {
      int4 q = lb[j];
      int idx = 4 * j;
      int p0 = atomicAdd(&cur[q.x], 1); perm[p0] = idx;
      int p1 = atomicAdd(&cur[q.y], 1); perm[p1] = idx + 1;
      int p2 = atomicAdd(&cur[q.z], 1); perm[p2] = idx + 2;
      int p3 = atomicAdd(&cur[q.w], 1); perm[p3] = idx + 3;
    }
  } else {
    const int b = blockIdx.x - 1;
    const float4* f4 = (const float4*)feat;
    const size_t rb = (size_t)b * ROWS_PER_B;
    float a0 = 0, a1 = 0, a2 = 0, a3 = 0, b0 = 0, b1 = 0, b2 = 0, b3 = 0;
#pragma unroll
    for (int r = 0; r < ROWS_PER_B; r += 4) {
      const float4* p0 = f4 + (rb + r) * 512;
      const float4* p1 = f4 + (rb + r + 1) * 512;
      const float4* p2 = f4 + (rb + r + 2) * 512;
      const float4* p3 = f4 + (rb + r + 3) * 512;
      float4 v0 = p0[t], u0 = p0[t + 256];
      float4 v1 = p1[t], u1 = p1[t + 256];
      float4 v2 = p2[t], u2 = p2[t + 256];
      float4 v3 = p3[t], u3 = p3[t + 256];
      a0 += (v0.x + v1.x) + (v2.x + v3.x);
      a1 += (v0.y + v1.y) + (v2.y + v3.y);
      a2 += (v0.z + v1.z) + (v2.z + v3.z);
      a3 += (v0.w + v1.w) + (v2.w + v3.w);
      b0 += (u0.x + u1.x) + (u2.x + u3.x);
      b1 += (u0.y + u1.y) + (u2.y + u3.y);
      b2 += (u0.z + u1.z) + (u2.z + u3.z);
      b3 += (u0.w + u1.w) + (u2.w + u3.w);
    }
    float4* o4 = (float4*)part_ov;
    o4[(size_t)b * 512 + t] = make_float4(a0, a1, a2, a3);
    o4[(size_t)b * 512 + 256 + t] = make_float4(b0, b1, b2, b3);
  }
}

// K2: fold COLB=2048 partials -> overall. 512 blocks, one float4-dim each
// (proven R10 structure, ~6 us).
__global__ __launch_bounds__(256) void k2_fold(const float* __restrict__ part_ov,
                                               float* __restrict__ overall) {
  const int fi = blockIdx.x;  // float4-dim index [0,512)
  const int tt = threadIdx.x;
  const float4* p4 = (const float4*)part_ov;
  float a0 = 0, a1 = 0, a2 = 0, a3 = 0;
#pragma unroll
  for (int j = 0; j < 8; ++j) {
    float4 v = p4[(size_t)(tt + 256 * j) * 512 + fi];
    a0 += v.x; a1 += v.y; a2 += v.z; a3 += v.w;
  }
  __shared__ float4 rbuf[256];
  rbuf[tt] = make_float4(a0, a1, a2, a3);
  __syncthreads();
  for (int s = 128; s; s >>= 1) {
    if (tt < s) {
      float4 o = rbuf[tt + s];
      rbuf[tt].x += o.x; rbuf[tt].y += o.y; rbuf[tt].z += o.z; rbuf[tt].w += o.w;
    }
    __syncthreads();
  }
  if (tt == 0) ((float4*)overall)[fi] = rbuf[0];
}

// K3: one block per class (R5's proven structure). Pass A: class sums (feat
// from L3) -> LDS + snorm. Pass B: wave per row, dots vs LDS sums + overall.
__global__ __launch_bounds__(256) void k3_class_pass(
    const float* __restrict__ feat, const int* __restrict__ offsets,
    const int* __restrict__ counts, const int* __restrict__ perm,
    const float* __restrict__ overall, float* __restrict__ pst,
    float* __restrict__ psw) {
  const int c = blockIdx.x, t = threadIdx.x, w = t >> 6, lane = t & 63;
  __shared__ int lperm[MAXCLS];
  __shared__ float sums_lds[FEAT];
  __shared__ float red[4];
  __shared__ float sc[2];  // {snorm, ovn}
  const int beg = offsets[c], n = counts[c];
  for (int i = t; i < n; i += 256) lperm[i] = perm[beg + i];

  // ovn = ||overall|| (redundant per block; 8 KB from L1/L2)
  const float4* ov4 = (const float4*)overall;
  {
    float4 o1 = ov4[t], o2 = ov4[t + 256];
    float sq = o1.x * o1.x + o1.y * o1.y + o1.z * o1.z + o1.w * o1.w +
               o2.x * o2.x + o2.y * o2.y + o2.z * o2.z + o2.w * o2.w;
    for (int off = 32; off; off >>= 1) sq += __shfl_xor(sq, off);
    if (lane == 0) red[w] = sq;
    __syncthreads();  // also covers lperm stores
    if (t == 0) sc[1] = sqrtf(red[0] + red[1] + red[2] + red[3]);
  }

  // pass A: class sums into registers (rows via lperm, feat L3-hot)
  const float4* f4 = (const float4*)feat;
  float a0 = 0, a1 = 0, a2 = 0, a3 = 0, b0 = 0, b1 = 0, b2 = 0, b3 = 0;
  int r = 0;
  for (; r + 4 <= n; r += 4) {
    const float4* p0 = f4 + (size_t)lperm[r] * 512;
    const float4* p1 = f4 + (size_t)lperm[r + 1] * 512;
    const float4* p2 = f4 + (size_t)lperm[r + 2] * 512;
    const float4* p3 = f4 + (size_t)lperm[r + 3] * 512;
    float4 v0 = p0[t], u0 = p0[t + 256];
    float4 v1 = p1[t], u1 = p1[t + 256];
    float4 v2 = p2[t], u2 = p2[t + 256];
    float4 v3 = p3[t], u3 = p3[t + 256];
    a0 += (v0.x + v1.x) + (v2.x + v3.x);
    a1 += (v0.y + v1.y) + (v2.y + v3.y);
    a2 += (v0.z + v1.z) + (v2.z + v3.z);
    a3 += (v0.w + v1.w) + (v2.w + v3.w);
    b0 += (u0.x + u1.x) + (u2.x + u3.x);
    b1 += (u0.y + u1.y) + (u2.y + u3.y);
    b2 += (u0.z + u1.z) + (u2.z + u3.z);
    b3 += (u0.w + u1.w) + (u2.w + u3.w);
  }
  for (; r < n; ++r) {
    const float4* p0 = f4 + (size_t)lperm[r] * 512;
    float4 v = p0[t], u = p0[t + 256];
    a0 += v.x; a1 += v.y; a2 += v.z; a3 += v.w;
    b0 += u.x; b1 += u.y; b2 += u.z; b3 += u.w;
  }
  float4* s4 = (float4*)sums_lds;
  s4[t] = make_float4(a0, a1, a2, a3);
  s4[t + 256] = make_float4(b0, b1, b2, b3);
  {
    float sq = a0 * a0 + a1 * a1 + a2 * a2 + a3 * a3 +
               b0 * b0 + b1 * b1 + b2 * b2 + b3 * b3;
    for (int off = 32; off; off >>= 1) sq += __shfl_xor(sq, off);
    __syncthreads();  // red[] reuse hazard: prior reduce fully consumed
    if (lane == 0) red[w] = sq;
    __syncthreads();
    if (t == 0) sc[0] = sqrtf(red[0] + red[1] + red[2] + red[3]);
    __syncthreads();  // sums_lds + sc ready for pass B
  }

  // pass B: wave per row (rows L2-hot from pass A)
  const float snormv = sc[0], ovn = sc[1];
  const float invN2 = 1.f / ((float)N_SAMPLES * (float)N_SAMPLES);
  const float cnt = (float)n;
  float st_acc = 0.f, sw_acc = 0.f;
  for (int rr = w; rr < n; rr += 4) {
    const float4* xr = f4 + (size_t)lperm[rr] * 512;
    float dxo = 0.f, dxs = 0.f, nx2 = 0.f;
#pragma unroll
    for (int k = 0; k < 8; ++k) {
      float4 x = xr[lane + 64 * k];
      float4 s = s4[lane + 64 * k];
      float4 o = ov4[lane + 64 * k];
      dxo += x.x * o.x + x.y * o.y + x.z * o.z + x.w * o.w;
      dxs += x.x * s.x + x.y * s.y + x.z * s.z + x.w * s.w;
      nx2 += x.x * x.x + x.y * x.y + x.z * x.z + x.w * x.w;
    }
    for (int off = 32; off; off >>= 1) {
      dxo += __shfl_xor(dxo, off);
      dxs += __shfl_xor(dxs, off);
      nx2 += __shfl_xor(nx2, off);
    }
    if (lane == 0) {
      float nx = sqrtf(nx2);
      float t1 = 1.f - dxo * ovn * invN2 / nx;
      float t2 = 1.f - dxs * snormv / (cnt * cnt * nx);
      st_acc += t1 * t1;
      sw_acc += t2 * t2;
    }
  }
  __shared__ float red2[8];
  if (lane == 0) { red2[w] = st_acc; red2[4 + w] = sw_acc; }
  __syncthreads();
  if (t == 0) {
    pst[c] = red2[0] + red2[1] + red2[2] + red2[3];
    psw[c] = red2[4] + red2[5] + red2[6] + red2[7];
  }
}

// K4: reduce NCLS partials x2 -> out
__global__ __launch_bounds__(256) void k4_final(const float* __restrict__ pst,
                                                const float* __restrict__ psw,
                                                float* __restrict__ out) {
  const int t = threadIdx.x, w = t >> 6, lane = t & 63;
  float st = 0.f, sw = 0.f;
  for (int i = t; i < NCLS; i += 256) { st += pst[i]; sw += psw[i]; }
  for (int off = 32; off; off >>= 1) {
    st += __shfl_xor(st, off);
    sw += __shfl_xor(sw, off);
  }
  __shared__ float rs[4], rw[4];
  if (lane == 0) { rs[w] = st; rw[w] = sw; }
  __syncthreads();
  if (t == 0) {
    float s = rs[0] + rs[1] + rs[2] + rs[3];
    float q = rw[0] + rw[1] + rw[2] + rw[3];
    float stv = s / (float)N_SAMPLES;
    float swv = q / ((float)N_SAMPLES * (float)NCLS);
    out[0] = stv;
    out[1] = swv;
    out[2] = stv - swv;
  }
}

extern "C" void kernel_launch(void* const* d_in, const int* in_sizes, int n_in,
                              void* d_out, int out_size, void* d_ws, size_t ws_size,
                              hipStream_t stream) {
  const float* feat = (const float*)d_in[0];
  const int* labels = (const int*)d_in[1];
  float* out = (float*)d_out;

  float* part_ov = (float*)d_ws;                 // COLB*FEAT (16 MB)
  float* overall = part_ov + (size_t)COLB * FEAT;  // FEAT
  float* pst = overall + FEAT;                   // CPAD
  float* psw = pst + CPAD;                       // CPAD
  int* counts = (int*)(psw + CPAD);              // CPAD
  int* offsets = counts + CPAD;                  // CPAD
  int* perm = offsets + CPAD;                    // N_SAMPLES

  k1_col_sort<<<COLB + 1, 256, 0, stream>>>(feat, labels, part_ov, counts,
                                            offsets, perm);
  k2_fold<<<512, 256, 0, stream>>>(part_ov, overall);
  k3_class_pass<<<NCLS, 256, 0, stream>>>(feat, offsets, counts, perm, overall,
                                          pst, psw);
  k4_final<<<1, 256, 0, stream>>>(pst, psw, out);
}